// Round 5
// baseline (293.999 us; speedup 1.0000x reference)
//
#include <hip/hip_runtime.h>
#include <hip/hip_bf16.h>

#define B_ROWS 1024
#define OBS_D  512
#define ACT_D  64
#define KD     128
#define CAT_D  192
#define CAP    131072

typedef __attribute__((ext_vector_type(8))) short bf16x8;
typedef __attribute__((ext_vector_type(4))) float f32x4;
typedef __attribute__((ext_vector_type(4))) unsigned int u32x4;

static __device__ __forceinline__ unsigned short f2bf(float x) {
  unsigned u = __float_as_uint(x);
  return (unsigned short)((u + 0x7fffu + ((u >> 16) & 1u)) >> 16);
}

static __device__ __forceinline__ f32x4 mfma16(bf16x8 a, bf16x8 b, f32x4 c) {
  return __builtin_amdgcn_mfma_f32_16x16x32_bf16(a, b, c, 0, 0, 0);
}

// trunc-split two fp32 into one packed-bf16 hi word and one lo word.
// x = hi + lo + eps, |eps| <= 2^-16 |x|  (cheap: no rounding adds)
static __device__ __forceinline__ void split2(float a, float b,
                                              unsigned& hw, unsigned& lw) {
  unsigned ua = __float_as_uint(a), ub = __float_as_uint(b);
  unsigned ha = ua & 0xffff0000u, hb = ub & 0xffff0000u;
  hw = (ua >> 16) | hb;
  float la = a - __uint_as_float(ha);
  float lb = b - __uint_as_float(hb);
  lw = (__float_as_uint(la) >> 16) | (__float_as_uint(lb) & 0xffff0000u);
}

// ---------------------------------------------------------------------------
// Kernel 1: fused MLP. Writes h_scaled = h * (1/tau * log2 e)  and
// hnorm = ||h_scaled|| (softmax shift in the exp2 domain).
// 4 rows/block -> 256 blocks (2x parallelism vs 8-row version).
// ---------------------------------------------------------------------------
#define MLP_ROWS 4

__global__ __launch_bounds__(256) void mlp_kernel(
    const float* __restrict__ obs, const float* __restrict__ action,
    const float* __restrict__ pred_W, const float* __restrict__ pred_b,
    const float* __restrict__ t1_W, const float* __restrict__ t1_b,
    const float* __restrict__ t2_W, const float* __restrict__ t2_b,
    const float* __restrict__ log_temp,
    float* __restrict__ h_out, float* __restrict__ hnorm) {
  __shared__ float s_obs[MLP_ROWS][OBS_D];
  __shared__ float s_in[MLP_ROWS][KD];
  __shared__ float s_cat[MLP_ROWS][CAT_D];
  __shared__ float s_h1[MLP_ROWS][KD];
  __shared__ float s_ho[MLP_ROWS][KD];
  __shared__ float s_norm[MLP_ROWS];

  const int t = threadIdx.x;
  const int row0 = blockIdx.x * MLP_ROWS;
  const float SCALE = expf(-log_temp[0]) * 1.44269504088896f;

  {
    const float4* g = (const float4*)(obs + (size_t)row0 * OBS_D);
    float4* s = (float4*)&s_obs[0][0];
    s[t] = g[t];
    s[t + 256] = g[t + 256];
  }
  __syncthreads();

  const int k  = t & 127;
  const int r0 = t >> 7;   // rows r0, r0+2

  {
    float acc[2] = {0.f, 0.f};
    const float4* w4 = (const float4*)(pred_W + (size_t)k * OBS_D);
    for (int d4 = 0; d4 < OBS_D / 4; ++d4) {
      float4 wv = w4[d4];
      #pragma unroll
      for (int p = 0; p < 2; ++p) {
        const float* sr = &s_obs[r0 + 2 * p][d4 * 4];
        acc[p] += wv.x * sr[0] + wv.y * sr[1] + wv.z * sr[2] + wv.w * sr[3];
      }
    }
    float b = pred_b[k];
    s_in[r0][k] = acc[0] + b;
    s_in[r0 + 2][k] = acc[1] + b;
  }
  __syncthreads();

  {
    int r = t >> 6, l = t & 63;
    float v0 = s_in[r][l], v1 = s_in[r][l + 64];
    float ss = v0 * v0 + v1 * v1;
    #pragma unroll
    for (int off = 32; off; off >>= 1) ss += __shfl_down(ss, off, 64);
    if (l == 0) s_norm[r] = fmaxf(sqrtf(ss), 1e-12f);
  }
  __syncthreads();

  #pragma unroll
  for (int it = 0; it < 3; ++it) {
    int i = t + it * 256;
    int r = i / CAT_D, c = i % CAT_D;
    float v = (c < KD) ? s_in[r][c] / s_norm[r]
                       : action[(size_t)(row0 + r) * ACT_D + (c - KD)];
    s_cat[r][c] = v;
  }
  __syncthreads();

  {
    float acc[2] = {0.f, 0.f};
    const float4* w4 = (const float4*)(t1_W + (size_t)k * CAT_D);
    for (int d4 = 0; d4 < CAT_D / 4; ++d4) {
      float4 wv = w4[d4];
      #pragma unroll
      for (int p = 0; p < 2; ++p) {
        const float* sr = &s_cat[r0 + 2 * p][d4 * 4];
        acc[p] += wv.x * sr[0] + wv.y * sr[1] + wv.z * sr[2] + wv.w * sr[3];
      }
    }
    float b = t1_b[k];
    s_h1[r0][k] = fmaxf(acc[0] + b, 0.f);
    s_h1[r0 + 2][k] = fmaxf(acc[1] + b, 0.f);
  }
  __syncthreads();

  {
    float acc[2] = {0.f, 0.f};
    const float4* w4 = (const float4*)(t2_W + (size_t)k * KD);
    for (int d4 = 0; d4 < KD / 4; ++d4) {
      float4 wv = w4[d4];
      #pragma unroll
      for (int p = 0; p < 2; ++p) {
        const float* sr = &s_h1[r0 + 2 * p][d4 * 4];
        acc[p] += wv.x * sr[0] + wv.y * sr[1] + wv.z * sr[2] + wv.w * sr[3];
      }
    }
    float b = t2_b[k];
    #pragma unroll
    for (int p = 0; p < 2; ++p) {
      float hv = (acc[p] + b) * SCALE;
      s_ho[r0 + 2 * p][k] = hv;
      h_out[(size_t)(row0 + r0 + 2 * p) * KD + k] = hv;
    }
  }
  __syncthreads();

  {
    int r = t >> 6, l = t & 63;
    float v0 = s_ho[r][l], v1 = s_ho[r][l + 64];
    float ss = v0 * v0 + v1 * v1;
    #pragma unroll
    for (int off = 32; off; off >>= 1) ss += __shfl_down(ss, off, 64);
    if (l == 0) hnorm[row0 + r] = sqrtf(ss);
  }
}

// ---------------------------------------------------------------------------
// Kernel 2 (MFMA, no LDS, no barriers, no preconv): block = 64 rows x 128
// keys/chunk, 4 waves each owning a disjoint 64row x 32key slice. B is read
// DIRECTLY from row-major fp32 keys (2 dwordx4 per lane per ks, one base
// address + imm offsets) and trunc-split to bf16 hi/lo in registers -- same
// bytes as a bf16-pair image, zero preprocessing pass. Register double-buffer
// (raw fp32) with split+MFMA+exp2 covering the prefetch latency.
// C = Ahi*Bh + Alo*Bh + Ahi*Bl (~2^-16 relative logits).
// ---------------------------------------------------------------------------
__global__ __launch_bounds__(256, 2) void score_mfma_kernel(
    const float* __restrict__ h, const float* __restrict__ hnorm,
    const float* __restrict__ keys, const float* __restrict__ values,
    float* __restrict__ accum, int chunks_per_block) {
  const int t = threadIdx.x;
  const int w = t >> 6, l = t & 63;
  const int lr = l & 15, lk = l >> 4;

  // bijective XCD grouping: xcd = blockIdx.x & 7 owns 4 consecutive
  // column slices; the 16 row-blocks of each slice land on the same XCD.
  const int i = blockIdx.x;
  const int idx2 = (i & 7) * 64 + (i >> 3);     // [0,512)
  const int col_slice = idx2 >> 4;              // [0,32)
  const int row_blk   = idx2 & 15;              // [0,16)
  const int row0   = row_blk * 64;
  const int chunk0 = col_slice * chunks_per_block;

  // ---- A fragments: 64 rows, RN hi/lo bf16 split, resident for all chunks
  bf16x8 Ahi[4][4], Alo[4][4];
  #pragma unroll
  for (int f = 0; f < 4; ++f) {
    const float* hr = h + (size_t)(row0 + f * 16 + lr) * KD + lk * 8;
    #pragma unroll
    for (int ks = 0; ks < 4; ++ks) {
      float4 xa = *(const float4*)(hr + ks * 32);
      float4 xb = *(const float4*)(hr + ks * 32 + 4);
      float xs[8] = {xa.x, xa.y, xa.z, xa.w, xb.x, xb.y, xb.z, xb.w};
      bf16x8 ah, al;
      #pragma unroll
      for (int q = 0; q < 8; ++q) {
        unsigned short hb = f2bf(xs[q]);
        float hf = __uint_as_float((unsigned)hb << 16);
        ah[q] = (short)hb;
        al[q] = (short)f2bf(xs[q] - hf);
      }
      Ahi[f][ks] = ah; Alo[f][ks] = al;
    }
  }

  // per-lane shift: max over the 4 f-rows sharing (lk,r). The shift is
  // common to s and q of each row, so it cancels exactly in q/s.
  float M[4];
  #pragma unroll
  for (int r = 0; r < 4; ++r) {
    float mm = hnorm[row0 + lk * 4 + r];
    #pragma unroll
    for (int f = 1; f < 4; ++f)
      mm = fmaxf(mm, hnorm[row0 + f * 16 + lk * 4 + r]);
    M[r] = mm;
  }

  float sacc[4][4], qacc[4][4];
  #pragma unroll
  for (int f = 0; f < 4; ++f)
    #pragma unroll
    for (int r = 0; r < 4; ++r) { sacc[f][r] = 0.f; qacc[f][r] = 0.f; }

  // per-lane base: key row (w*32 + lr), dim block lk*8 floats = lk*32 bytes.
  const char* kbase = (const char*)keys
      + ((size_t)chunk0 * 128 + w * 32 + lr) * 512 + lk * 32;
  const float* vbase = values + (size_t)chunk0 * 128 + w * 32 + lr;

  f32x4 RA[8], RB[8];
  bf16x8 Bh[4], Bl[4];
  float vA, vB;

#define LOADR(R, V, BOFF, VOFF)                                          \
  {                                                                      \
    const char* p_ = kbase + (BOFF);                                     \
    _Pragma("unroll")                                                    \
    for (int ks_ = 0; ks_ < 4; ++ks_) {                                  \
      R[2 * ks_]     = *(const f32x4*)(p_ + ks_ * 128);                  \
      R[2 * ks_ + 1] = *(const f32x4*)(p_ + ks_ * 128 + 16);             \
    }                                                                    \
    V = vbase[(VOFF)];                                                   \
  }

#define SPLITB(R)                                                        \
  {                                                                      \
    _Pragma("unroll")                                                    \
    for (int ks_ = 0; ks_ < 4; ++ks_) {                                  \
      unsigned h0_, h1_, h2_, h3_, l0_, l1_, l2_, l3_;                   \
      split2(R[2 * ks_].x,     R[2 * ks_].y,     h0_, l0_);              \
      split2(R[2 * ks_].z,     R[2 * ks_].w,     h1_, l1_);              \
      split2(R[2 * ks_ + 1].x, R[2 * ks_ + 1].y, h2_, l2_);              \
      split2(R[2 * ks_ + 1].z, R[2 * ks_ + 1].w, h3_, l3_);              \
      u32x4 th_ = {h0_, h1_, h2_, h3_};                                  \
      u32x4 tl_ = {l0_, l1_, l2_, l3_};                                  \
      Bh[ks_] = __builtin_bit_cast(bf16x8, th_);                         \
      Bl[ks_] = __builtin_bit_cast(bf16x8, tl_);                         \
    }                                                                    \
  }

#define COMPUTE(V)                                                       \
  {                                                                      \
    f32x4 C[4];                                                          \
    _Pragma("unroll")                                                    \
    for (int f_ = 0; f_ < 4; ++f_) C[f_] = (f32x4){0.f, 0.f, 0.f, 0.f};  \
    _Pragma("unroll")                                                    \
    for (int ks_ = 0; ks_ < 4; ++ks_) {                                  \
      _Pragma("unroll")                                                  \
      for (int f_ = 0; f_ < 4; ++f_)                                     \
        C[f_] = mfma16(Ahi[f_][ks_], Bh[ks_], C[f_]);                    \
      _Pragma("unroll")                                                  \
      for (int f_ = 0; f_ < 4; ++f_)                                     \
        C[f_] = mfma16(Alo[f_][ks_], Bh[ks_], C[f_]);                    \
      _Pragma("unroll")                                                  \
      for (int f_ = 0; f_ < 4; ++f_)                                     \
        C[f_] = mfma16(Ahi[f_][ks_], Bl[ks_], C[f_]);                    \
    }                                                                    \
    _Pragma("unroll")                                                    \
    for (int f_ = 0; f_ < 4; ++f_) {                                     \
      _Pragma("unroll")                                                  \
      for (int r_ = 0; r_ < 4; ++r_) {                                   \
        float e_ = __builtin_amdgcn_exp2f(C[f_][r_] - M[r_]);            \
        sacc[f_][r_] += e_;                                              \
        qacc[f_][r_] = fmaf(e_, (V), qacc[f_][r_]);                      \
      }                                                                  \
    }                                                                    \
  }

  LOADR(RA, vA, 0, 0);

  for (int ck = 0; ck < chunks_per_block; ++ck) {
    const size_t co = (size_t)ck << 16;              // ck * 128 keys * 512 B
    LOADR(RB, vB, co + 8192, ck * 128 + 16);         // prefetch g=1
    SPLITB(RA);
    COMPUTE(vA);                                     // compute g=0
    const int last = (ck + 1 >= chunks_per_block);
    const size_t cn = last ? co : co + 65536;
    const int vn = last ? ck * 128 : (ck + 1) * 128;
    LOADR(RA, vA, cn, vn);                           // prefetch next g=0
    SPLITB(RB);
    COMPUTE(vB);                                     // compute g=1
  }

#undef LOADR
#undef SPLITB
#undef COMPUTE

  #pragma unroll
  for (int f = 0; f < 4; ++f)
    #pragma unroll
    for (int r = 0; r < 4; ++r) {
      float s = sacc[f][r], q = qacc[f][r];
      #pragma unroll
      for (int off = 8; off; off >>= 1) {
        s += __shfl_down(s, off, 16);
        q += __shfl_down(q, off, 16);
      }
      if (lr == 0) {
        int row = row0 + f * 16 + lk * 4 + r;
        atomicAdd(&accum[(size_t)row * 2 + 0], s);
        atomicAdd(&accum[(size_t)row * 2 + 1], q);
      }
    }
}

// ---------------------------------------------------------------------------
// Kernel 3: out = q / s
// ---------------------------------------------------------------------------
__global__ void finalize_kernel(const float* __restrict__ accum,
                                float* __restrict__ out) {
  int b = blockIdx.x * 256 + threadIdx.x;
  if (b < B_ROWS) out[b] = accum[(size_t)b * 2 + 1] / accum[(size_t)b * 2 + 0];
}

// ---------------------------------------------------------------------------
extern "C" void kernel_launch(void* const* d_in, const int* in_sizes, int n_in,
                              void* d_out, int out_size, void* d_ws, size_t ws_size,
                              hipStream_t stream) {
  const float* obs      = (const float*)d_in[0];
  const float* action   = (const float*)d_in[1];
  const float* pred_W   = (const float*)d_in[2];
  const float* pred_b   = (const float*)d_in[3];
  const float* t1_W     = (const float*)d_in[4];
  const float* t1_b     = (const float*)d_in[5];
  const float* t2_W     = (const float*)d_in[6];
  const float* t2_b     = (const float*)d_in[7];
  const float* keys     = (const float*)d_in[8];
  const float* values   = (const float*)d_in[9];
  const float* log_temp = (const float*)d_in[10];
  float* out = (float*)d_out;

  float* h     = (float*)d_ws;             // 1024*128 f32 = 512 KB
  float* hnorm = h + (size_t)B_ROWS * KD;  // 4 KB
  float* accum = hnorm + B_ROWS;           // 8 KB

  hipMemsetAsync(accum, 0, (size_t)B_ROWS * 2 * sizeof(float), stream);

  hipLaunchKernelGGL(mlp_kernel, dim3(B_ROWS / MLP_ROWS), dim3(256), 0, stream,
                     obs, action, pred_W, pred_b, t1_W, t1_b, t2_W, t2_b,
                     log_temp, h, hnorm);

  const int XB = 32;                        // column slices
  hipLaunchKernelGGL(score_mfma_kernel, dim3(XB * (B_ROWS / 64)), dim3(256),
                     0, stream, h, hnorm, keys, values, accum,
                     (CAP / 128) / XB);

  hipLaunchKernelGGL(finalize_kernel, dim3(4), dim3(256), 0, stream, accum, out);
}